// Round 1
// baseline (401.738 us; speedup 1.0000x reference)
//
#include <hip/hip_runtime.h>

typedef __bf16 bf16;
typedef __bf16 bf16x8 __attribute__((ext_vector_type(8)));
typedef __bf16 bf16x4 __attribute__((ext_vector_type(4)));
typedef float f32x4 __attribute__((ext_vector_type(4)));

static __device__ __forceinline__ f32x4 mfma16(bf16x8 a, bf16x8 b, f32x4 c) {
  return __builtin_amdgcn_mfma_f32_16x16x32_bf16(a, b, c, 0, 0, 0);
}

// load 8 consecutive f32, convert to bf16x8 fragment
static __device__ __forceinline__ bf16x8 ld_bf8(const float* __restrict__ p) {
  f32x4 a = *(const f32x4*)p;
  f32x4 b = *(const f32x4*)(p + 4);
  bf16x8 r;
  r[0] = (bf16)a[0]; r[1] = (bf16)a[1]; r[2] = (bf16)a[2]; r[3] = (bf16)a[3];
  r[4] = (bf16)b[0]; r[5] = (bf16)b[1]; r[6] = (bf16)b[2]; r[7] = (bf16)b[3];
  return r;
}

// ---------------------------------------------------------------- k0: rpb gather
__global__ void k0_rpb(const float* __restrict__ bt, const int* __restrict__ ri,
                       float* __restrict__ rpb) {
  int t = blockIdx.x * 256 + threadIdx.x;  // 0..65535
  int idx = ri[t];
  f32x4 v = *(const f32x4*)(bt + idx * 4);
#pragma unroll
  for (int h = 0; h < 4; ++h) rpb[h * 65536 + t] = v[h];
}

// ---------------------------------------------------------------- k1: fused QKV
__global__ void __launch_bounds__(256, 2)
k1_qkv(const float* __restrict__ x, const float* __restrict__ qw,
       const float* __restrict__ qb, bf16* __restrict__ q_s,
       bf16* __restrict__ k_s, bf16* __restrict__ vt) {
  const int tid = threadIdx.x;
  const int wv = tid >> 6, ln = tid & 15, qd = (tid >> 4) & 3;
  const int b = blockIdx.x >> 1;
  const int row0 = (blockIdx.x & 1) * 128 + (wv >> 1) * 64;
  const int cg = wv & 1;

  bf16x8 xf[4][4];  // [nt][ks]
#pragma unroll
  for (int nt = 0; nt < 4; ++nt)
#pragma unroll
    for (int ks = 0; ks < 4; ++ks)
      xf[nt][ks] = ld_bf8(x + (size_t)(b * 256 + row0 + nt * 16 + ln) * 128 +
                          ks * 32 + qd * 8);

  // chunks 0,1 = q,k : transposed (D = W . X^T)
#pragma unroll
  for (int ch = 0; ch < 2; ++ch) {
    f32x4 acc[4][4];
#pragma unroll
    for (int mt = 0; mt < 4; ++mt)
#pragma unroll
      for (int nt = 0; nt < 4; ++nt) acc[mt][nt] = (f32x4){0.f, 0.f, 0.f, 0.f};
#pragma unroll
    for (int mt = 0; mt < 4; ++mt)
#pragma unroll
      for (int ks = 0; ks < 4; ++ks) {
        bf16x8 wf = ld_bf8(qw + (size_t)(ch * 128 + cg * 64 + mt * 16 + ln) * 128 +
                           ks * 32 + qd * 8);
#pragma unroll
        for (int nt = 0; nt < 4; ++nt) acc[mt][nt] = mfma16(wf, xf[nt][ks], acc[mt][nt]);
      }
    bf16* dst = ch ? k_s : q_s;
    const float scl = ch ? 1.0f : 0.17677669529663689f;
#pragma unroll
    for (int mt = 0; mt < 4; ++mt) {
      const int c0 = cg * 64 + mt * 16 + qd * 4;
      f32x4 b4 = *(const f32x4*)(qb + ch * 128 + c0);
      const int hh = c0 >> 5, d0 = c0 & 31;
#pragma unroll
      for (int nt = 0; nt < 4; ++nt) {
        const int nr = row0 + nt * 16 + ln;
        bf16x4 o;
#pragma unroll
        for (int r = 0; r < 4; ++r) o[r] = (bf16)((acc[mt][nt][r] + b4[r]) * scl);
        *(bf16x4*)(dst + (size_t)((b * 4 + hh) * 256 + nr) * 32 + d0) = o;
      }
    }
  }

  // chunk 2 = v : normal orientation -> V^T store
  f32x4 av[4][4];
#pragma unroll
  for (int nt = 0; nt < 4; ++nt)
#pragma unroll
    for (int mt = 0; mt < 4; ++mt) av[nt][mt] = (f32x4){0.f, 0.f, 0.f, 0.f};
#pragma unroll
  for (int ks = 0; ks < 4; ++ks)
#pragma unroll
    for (int mt = 0; mt < 4; ++mt) {
      bf16x8 wf = ld_bf8(qw + (size_t)(256 + cg * 64 + mt * 16 + ln) * 128 +
                         ks * 32 + qd * 8);
#pragma unroll
      for (int nt = 0; nt < 4; ++nt) av[nt][mt] = mfma16(xf[nt][ks], wf, av[nt][mt]);
    }
#pragma unroll
  for (int nt = 0; nt < 4; ++nt)
#pragma unroll
    for (int mt = 0; mt < 4; ++mt) {
      const int c = cg * 64 + mt * 16 + ln;
      const float bb = qb[256 + c];
      const int hh = c >> 5, dd = c & 31;
      const int n0 = row0 + nt * 16 + qd * 4;
      bf16x4 o;
#pragma unroll
      for (int r = 0; r < 4; ++r) o[r] = (bf16)(av[nt][mt][r] + bb);
      *(bf16x4*)(vt + (size_t)((b * 4 + hh) * 32 + dd) * 256 + n0) = o;
    }
}

// ---------------------------------------------------------------- k2: attention
// grid 1024: bid = rr*256 + h*64 + w ; rr = q-quarter (4 stripes, one per wave)
// No K/V LDS staging (they fit L1/L2), psm only (32KB), zero barriers.
// S^T = K.Q^T orientation: each lane's 64 logits share one q-row -> softmax = 2 shfl_xor
__global__ void __launch_bounds__(256, 4)
k2_attn(const bf16* __restrict__ q_s, const bf16* __restrict__ k_s,
        const bf16* __restrict__ vt, const float* __restrict__ mask,
        const float* __restrict__ rpb, float* __restrict__ aof,
        bf16* __restrict__ aob, const int use_bf) {
  __shared__ bf16 psm[4 * 16 * 256];  // per-wave private 8KB P tiles, xor-swizzled
  const int tid = threadIdx.x, wv = tid >> 6;
  const int ln = tid & 15, qd = (tid >> 4) & 3;
  const int w = blockIdx.x & 63, h = (blockIdx.x >> 6) & 3, rr = blockIdx.x >> 8;
  const int s = rr * 4 + wv;   // stripe 0..15 -> q rows [s*16, s*16+16)
  const int n = s * 16 + ln;   // this lane's q-row

  // mask[w]+rpb[h] for this wave's stripe, packed bf16 (32 VGPRs)
  bf16x4 cmb[16];
#pragma unroll
  for (int mt = 0; mt < 16; ++mt) {
    f32x4 m4 = *(const f32x4*)(mask + (size_t)(w * 256 + n) * 256 + mt * 16 + qd * 4);
    f32x4 r4 = *(const f32x4*)(rpb + (size_t)h * 65536 + n * 256 + mt * 16 + qd * 4);
    bf16x4 cv;
#pragma unroll
    for (int r = 0; r < 4; ++r) cv[r] = (bf16)(m4[r] + r4[r]);
    cmb[mt] = cv;
  }

  bf16* pb = psm + wv * 4096 + ln * 256;

  for (int ib = 0; ib < 8; ++ib) {
    const int b = w + ib * 64;
    const size_t base = (size_t)(b * 4 + h) * 8192;
    const bf16* kp = k_s + base;
    const bf16* vp = vt + base;
    bf16x8 qf = *(const bf16x8*)(q_s + base + (size_t)n * 32 + qd * 8);

    f32x4 acc[16];
#pragma unroll
    for (int mt = 0; mt < 16; ++mt) acc[mt] = (f32x4){0.f, 0.f, 0.f, 0.f};
#pragma unroll
    for (int mt = 0; mt < 16; ++mt) {  // K direct from global: 1KB contiguous/wave/mt
      bf16x8 af = *(const bf16x8*)(kp + (mt * 16 + ln) * 32 + qd * 8);
      acc[mt] = mfma16(af, qf, acc[mt]);  // lane: k=mt*16+qd*4+r, qrow=ln
    }
    float sum = 0.f;
#pragma unroll
    for (int mt = 0; mt < 16; ++mt) {  // logits + exp (no max-sub: |logit| < ~8)
      bf16x4 pv;
#pragma unroll
      for (int r = 0; r < 4; ++r) {
        float p = __expf(acc[mt][r] + (float)cmb[mt][r]);
        sum += p;
        pv[r] = (bf16)p;
      }
      *(bf16x4*)(pb + (((mt * 2 + (qd >> 1)) ^ (ln & 7)) * 8) + (qd & 1) * 4) = pv;
    }
    sum += __shfl_xor(sum, 16);
    sum += __shfl_xor(sum, 32);
    const float linv = 1.0f / sum;

    f32x4 accO[2];
    accO[0] = (f32x4){0.f, 0.f, 0.f, 0.f};
    accO[1] = (f32x4){0.f, 0.f, 0.f, 0.f};
#pragma unroll
    for (int kt = 0; kt < 8; ++kt) {  // O = P.V, V^T direct from global
      bf16x8 pf = *(const bf16x8*)(pb + (((kt * 4 + qd) ^ (ln & 7)) * 8));
#pragma unroll
      for (int ct = 0; ct < 2; ++ct) {
        const int d = ct * 16 + ln;
        bf16x8 vf = *(const bf16x8*)(vp + d * 256 + kt * 32 + qd * 8);
        accO[ct] = mfma16(pf, vf, accO[ct]);
      }
    }
#pragma unroll
    for (int r = 0; r < 4; ++r) {
      const float lb = __shfl(linv, qd * 4 + r);  // row's denom lives at lane ln==row
      const size_t orow = (size_t)(b * 256 + s * 16 + qd * 4 + r) * 128 + h * 32;
      if (use_bf) {
#pragma unroll
        for (int ct = 0; ct < 2; ++ct)
          aob[orow + ct * 16 + ln] = (bf16)(accO[ct][r] * lb);
      } else {
#pragma unroll
        for (int ct = 0; ct < 2; ++ct) aof[orow + ct * 16 + ln] = accO[ct][r] * lb;
      }
    }
  }
}

// ---------------------------------------------------------------- k3: proj
// use_bf: read bf16 ao from workspace; else f32 in-place on d_out (original path)
__global__ void __launch_bounds__(256, 2)
k3_proj(const float* __restrict__ xf32, const bf16* __restrict__ xb16,
        const int use_bf, const float* __restrict__ pw,
        const float* __restrict__ pbias, float* __restrict__ out) {
  const int tid = threadIdx.x;
  const int wv = tid >> 6, ln = tid & 15, qd = (tid >> 4) & 3;
  const int cg = wv & 1;
  const size_t row0 = (size_t)blockIdx.x * 128 + (wv >> 1) * 64;

  bf16x8 xf[4][4];
#pragma unroll
  for (int nt = 0; nt < 4; ++nt)
#pragma unroll
    for (int ks = 0; ks < 4; ++ks) {
      const size_t off = (row0 + nt * 16 + ln) * 128 + ks * 32 + qd * 8;
      if (use_bf)
        xf[nt][ks] = *(const bf16x8*)(xb16 + off);
      else
        xf[nt][ks] = ld_bf8(xf32 + off);
    }
  __syncthreads();  // in-place safety for the f32 fallback path

  f32x4 acc[4][4];
#pragma unroll
  for (int mt = 0; mt < 4; ++mt)
#pragma unroll
    for (int nt = 0; nt < 4; ++nt) acc[mt][nt] = (f32x4){0.f, 0.f, 0.f, 0.f};
#pragma unroll
  for (int mt = 0; mt < 4; ++mt)
#pragma unroll
    for (int ks = 0; ks < 4; ++ks) {
      bf16x8 wf = ld_bf8(pw + (size_t)(cg * 64 + mt * 16 + ln) * 128 + ks * 32 + qd * 8);
#pragma unroll
      for (int nt = 0; nt < 4; ++nt) acc[mt][nt] = mfma16(wf, xf[nt][ks], acc[mt][nt]);
    }
#pragma unroll
  for (int mt = 0; mt < 4; ++mt) {
    const int c0 = cg * 64 + mt * 16 + qd * 4;
    f32x4 b4 = *(const f32x4*)(pbias + c0);
#pragma unroll
    for (int nt = 0; nt < 4; ++nt) {
      f32x4 o;
#pragma unroll
      for (int r = 0; r < 4; ++r) o[r] = acc[mt][nt][r] + b4[r];
      *(f32x4*)(out + (row0 + nt * 16 + ln) * 128 + c0) = o;
    }
  }
}

// ----------------------------------------------------------------
extern "C" void kernel_launch(void* const* d_in, const int* in_sizes, int n_in,
                              void* d_out, int out_size, void* d_ws, size_t ws_size,
                              hipStream_t stream) {
  const float* x = (const float*)d_in[0];
  const float* mask = (const float*)d_in[1];
  const float* qkv_w = (const float*)d_in[2];
  const float* qkv_b = (const float*)d_in[3];
  const float* proj_w = (const float*)d_in[4];
  const float* proj_b = (const float*)d_in[5];
  const float* bias_table = (const float*)d_in[6];
  const int* rel_idx = (const int*)d_in[7];

  char* ws = (char*)d_ws;
  bf16* q_s = (bf16*)ws;                          // (B,H,256,32) bf16  33.5 MB
  bf16* k_s = (bf16*)(ws + 33554432);             // (B,H,256,32) bf16  33.5 MB
  bf16* vt = (bf16*)(ws + 2ll * 33554432);        // (B,H,32,256) bf16  33.5 MB
  float* rpb = (float*)(ws + 3ll * 33554432);     // (4,256,256)  f32    1 MB
  // bf16 attention-out staging (33.5 MB) if workspace allows, else f32 in d_out
  const size_t WS_NEED = 3ull * 33554432 + 1048576 + 33554432;
  const int use_bf = (ws_size >= WS_NEED) ? 1 : 0;
  bf16* aob = (bf16*)(ws + 3ll * 33554432 + 1048576);
  float* aof = (float*)d_out;

  k0_rpb<<<dim3(256), dim3(256), 0, stream>>>(bias_table, rel_idx, rpb);
  k1_qkv<<<dim3(1024), dim3(256), 0, stream>>>(x, qkv_w, qkv_b, q_s, k_s, vt);
  k2_attn<<<dim3(1024), dim3(256), 0, stream>>>(q_s, k_s, vt, mask, rpb, aof, aob, use_bf);
  k3_proj<<<dim3(1024), dim3(256), 0, stream>>>(aof, aob, use_bf, proj_w, proj_b,
                                                (float*)d_out);
}

// Round 2
// 308.939 us; speedup vs baseline: 1.3004x; 1.3004x over previous
//
#include <hip/hip_runtime.h>

typedef __bf16 bf16;
typedef __bf16 bf16x8 __attribute__((ext_vector_type(8)));
typedef __bf16 bf16x4 __attribute__((ext_vector_type(4)));
typedef float f32x4 __attribute__((ext_vector_type(4)));

static __device__ __forceinline__ f32x4 mfma16(bf16x8 a, bf16x8 b, f32x4 c) {
  return __builtin_amdgcn_mfma_f32_16x16x32_bf16(a, b, c, 0, 0, 0);
}

// load 8 consecutive f32, convert to bf16x8 fragment
static __device__ __forceinline__ bf16x8 ld_bf8(const float* __restrict__ p) {
  f32x4 a = *(const f32x4*)p;
  f32x4 b = *(const f32x4*)(p + 4);
  bf16x8 r;
  r[0] = (bf16)a[0]; r[1] = (bf16)a[1]; r[2] = (bf16)a[2]; r[3] = (bf16)a[3];
  r[4] = (bf16)b[0]; r[5] = (bf16)b[1]; r[6] = (bf16)b[2]; r[7] = (bf16)b[3];
  return r;
}

// ---------------------------------------------------------------- k0: prep
// mb = bf16(mask) (64,256,256) in d_out scratch; rb = bf16 rpb (4,256,256)
__global__ void k0_prep(const float* __restrict__ mask, const float* __restrict__ bt,
                        const int* __restrict__ ri, bf16* __restrict__ mb,
                        bf16* __restrict__ rb) {
  int t = blockIdx.x * 256 + threadIdx.x;  // 0..1048575, 4 f32 each
  f32x4 m4 = *(const f32x4*)(mask + (size_t)t * 4);
  bf16x4 o;
#pragma unroll
  for (int r = 0; r < 4; ++r) o[r] = (bf16)m4[r];
  *(bf16x4*)(mb + (size_t)t * 4) = o;
  if (t < 65536) {
    int idx = ri[t];
    f32x4 v = *(const f32x4*)(bt + idx * 4);
#pragma unroll
    for (int h = 0; h < 4; ++h) rb[h * 65536 + t] = (bf16)v[h];
  }
}

// ---------------------------------------------------------------- k1: fused QKV
__global__ void __launch_bounds__(256, 2)
k1_qkv(const float* __restrict__ x, const float* __restrict__ qw,
       const float* __restrict__ qb, bf16* __restrict__ q_s,
       bf16* __restrict__ k_s, bf16* __restrict__ vt) {
  const int tid = threadIdx.x;
  const int wv = tid >> 6, ln = tid & 15, qd = (tid >> 4) & 3;
  const int b = blockIdx.x >> 1;
  const int row0 = (blockIdx.x & 1) * 128 + (wv >> 1) * 64;
  const int cg = wv & 1;

  bf16x8 xf[4][4];  // [nt][ks]
#pragma unroll
  for (int nt = 0; nt < 4; ++nt)
#pragma unroll
    for (int ks = 0; ks < 4; ++ks)
      xf[nt][ks] = ld_bf8(x + (size_t)(b * 256 + row0 + nt * 16 + ln) * 128 +
                          ks * 32 + qd * 8);

  // chunks 0,1 = q,k : transposed (D = W . X^T)
#pragma unroll
  for (int ch = 0; ch < 2; ++ch) {
    f32x4 acc[4][4];
#pragma unroll
    for (int mt = 0; mt < 4; ++mt)
#pragma unroll
      for (int nt = 0; nt < 4; ++nt) acc[mt][nt] = (f32x4){0.f, 0.f, 0.f, 0.f};
#pragma unroll
    for (int mt = 0; mt < 4; ++mt)
#pragma unroll
      for (int ks = 0; ks < 4; ++ks) {
        bf16x8 wf = ld_bf8(qw + (size_t)(ch * 128 + cg * 64 + mt * 16 + ln) * 128 +
                           ks * 32 + qd * 8);
#pragma unroll
        for (int nt = 0; nt < 4; ++nt) acc[mt][nt] = mfma16(wf, xf[nt][ks], acc[mt][nt]);
      }
    bf16* dst = ch ? k_s : q_s;
    const float scl = ch ? 1.0f : 0.17677669529663689f;
#pragma unroll
    for (int mt = 0; mt < 4; ++mt) {
      const int c0 = cg * 64 + mt * 16 + qd * 4;
      f32x4 b4 = *(const f32x4*)(qb + ch * 128 + c0);
      const int hh = c0 >> 5, d0 = c0 & 31;
#pragma unroll
      for (int nt = 0; nt < 4; ++nt) {
        const int nr = row0 + nt * 16 + ln;
        bf16x4 o;
#pragma unroll
        for (int r = 0; r < 4; ++r) o[r] = (bf16)((acc[mt][nt][r] + b4[r]) * scl);
        *(bf16x4*)(dst + (size_t)((b * 4 + hh) * 256 + nr) * 32 + d0) = o;
      }
    }
  }

  // chunk 2 = v : normal orientation -> V^T store
  f32x4 av[4][4];
#pragma unroll
  for (int nt = 0; nt < 4; ++nt)
#pragma unroll
    for (int mt = 0; mt < 4; ++mt) av[nt][mt] = (f32x4){0.f, 0.f, 0.f, 0.f};
#pragma unroll
  for (int ks = 0; ks < 4; ++ks)
#pragma unroll
    for (int mt = 0; mt < 4; ++mt) {
      bf16x8 wf = ld_bf8(qw + (size_t)(256 + cg * 64 + mt * 16 + ln) * 128 +
                         ks * 32 + qd * 8);
#pragma unroll
      for (int nt = 0; nt < 4; ++nt) av[nt][mt] = mfma16(xf[nt][ks], wf, av[nt][mt]);
    }
#pragma unroll
  for (int nt = 0; nt < 4; ++nt)
#pragma unroll
    for (int mt = 0; mt < 4; ++mt) {
      const int c = cg * 64 + mt * 16 + ln;
      const float bb = qb[256 + c];
      const int hh = c >> 5, dd = c & 31;
      const int n0 = row0 + nt * 16 + qd * 4;
      bf16x4 o;
#pragma unroll
      for (int r = 0; r < 4; ++r) o[r] = (bf16)(av[nt][mt][r] + bb);
      *(bf16x4*)(vt + (size_t)((b * 4 + hh) * 32 + dd) * 256 + n0) = o;
    }
}

// ---------------------------------------------------------------- k2: attention
// grid 512: bid = rh*256 + h*64 + w ; 256 threads (4 waves, 2 stripes of 16 q-rows)
// S^T = K.Q^T orientation: each lane's 64 logits share one q-row -> softmax = 2 shfl_xor
// ao written bf16 INTO q_s (B,H,N,32) layout: same-wave WAR on fully-consumed Q stripe.
__global__ void __launch_bounds__(256, 2)
k2_attn(bf16* __restrict__ q_s, const bf16* __restrict__ k_s,
        const bf16* __restrict__ vt, const bf16* __restrict__ mb,
        const bf16* __restrict__ rb) {
  __shared__ bf16 ksm[256 * 32];      // K, xor-swizzled 16B blocks
  __shared__ bf16 vsm[32 * 256];      // V^T, xor-swizzled
  __shared__ bf16 psm[4 * 16 * 256];  // P per wave, xor-swizzled
  const int tid = threadIdx.x, wv = tid >> 6;
  const int ln = tid & 15, qd = (tid >> 4) & 3;
  const int w = blockIdx.x & 63, h = (blockIdx.x >> 6) & 3, rh = blockIdx.x >> 8;

  // mask[w]+rpb[h] for this wave's 2 stripes, bf16 loads (8B/lane each)
  bf16x4 cmb[2][16];
#pragma unroll
  for (int si = 0; si < 2; ++si) {
    const int n = (rh * 8 + wv * 2 + si) * 16 + ln;
#pragma unroll
    for (int mt = 0; mt < 16; ++mt) {
      bf16x4 m4 = *(const bf16x4*)(mb + (size_t)(w * 256 + n) * 256 + mt * 16 + qd * 4);
      bf16x4 r4 = *(const bf16x4*)(rb + (size_t)h * 65536 + n * 256 + mt * 16 + qd * 4);
      bf16x4 cv;
#pragma unroll
      for (int r = 0; r < 4; ++r) cv[r] = (bf16)((float)m4[r] + (float)r4[r]);
      cmb[si][mt] = cv;
    }
  }

  for (int ib = 0; ib < 8; ++ib) {
    const int b = w + ib * 64;
    const bf16* kp = k_s + (size_t)(b * 4 + h) * 8192;
    const bf16* vp = vt + (size_t)(b * 4 + h) * 8192;
    __syncthreads();
#pragma unroll
    for (int i = 0; i < 4; ++i) {  // stage K and V^T (16KB each) with swizzle
      const int ci = i * 256 + tid;
      {
        const int r_ = ci >> 2, cb = ci & 3;
        *(bf16x8*)(ksm + r_ * 32 + ((cb ^ (r_ & 3)) * 8)) =
            *(const bf16x8*)(kp + r_ * 32 + cb * 8);
      }
      {
        const int r_ = ci >> 5, cb = ci & 31;
        *(bf16x8*)(vsm + r_ * 256 + ((cb ^ (r_ & 7)) * 8)) =
            *(const bf16x8*)(vp + r_ * 256 + cb * 8);
      }
    }
    __syncthreads();

#pragma unroll
    for (int si = 0; si < 2; ++si) {
      const int s = rh * 8 + wv * 2 + si;
      bf16x8 qf = *(const bf16x8*)(q_s + (size_t)(b * 4 + h) * 8192 +
                                   (s * 16 + ln) * 32 + qd * 8);
      f32x4 acc[16];
#pragma unroll
      for (int mt = 0; mt < 16; ++mt) acc[mt] = (f32x4){0.f, 0.f, 0.f, 0.f};
#pragma unroll
      for (int mt = 0; mt < 16; ++mt) {
        const int m = mt * 16 + ln;
        bf16x8 af = *(const bf16x8*)(ksm + m * 32 + ((qd ^ (m & 3)) * 8));
        acc[mt] = mfma16(af, qf, acc[mt]);  // S^T tile: lane: k=mt*16+qd*4+r, qrow=ln
      }
      float sum = 0.f;
      bf16* pb = psm + wv * 4096 + ln * 256;
#pragma unroll
      for (int mt = 0; mt < 16; ++mt) {  // logits + exp (no max-sub: |logit| < ~8)
        bf16x4 pv;
#pragma unroll
        for (int r = 0; r < 4; ++r) {
          float p = __expf(acc[mt][r] + (float)cmb[si][mt][r]);
          sum += p;
          pv[r] = (bf16)p;
        }
        *(bf16x4*)(pb + (((mt * 2 + (qd >> 1)) ^ (ln & 7)) * 8) + (qd & 1) * 4) = pv;
      }
      sum += __shfl_xor(sum, 16);
      sum += __shfl_xor(sum, 32);
      const float linv = 1.0f / sum;

      f32x4 accO[2];
      accO[0] = (f32x4){0.f, 0.f, 0.f, 0.f};
      accO[1] = (f32x4){0.f, 0.f, 0.f, 0.f};
#pragma unroll
      for (int kt = 0; kt < 8; ++kt) {  // O = P.V
        bf16x8 pf = *(const bf16x8*)(pb + (((kt * 4 + qd) ^ (ln & 7)) * 8));
#pragma unroll
        for (int ct = 0; ct < 2; ++ct) {
          const int d = ct * 16 + ln;
          bf16x8 vf = *(const bf16x8*)(vsm + d * 256 + (((kt * 4 + qd) ^ (d & 7)) * 8));
          accO[ct] = mfma16(pf, vf, accO[ct]);
        }
      }
      // ao (bf16) overwrites this wave's consumed Q stripe: (B,H,N,32) layout
#pragma unroll
      for (int r = 0; r < 4; ++r) {
        const float lb = __shfl(linv, qd * 4 + r);  // row's denom lives at lane ln==row
        const size_t obase =
            (size_t)(b * 4 + h) * 8192 + (size_t)(s * 16 + qd * 4 + r) * 32;
#pragma unroll
        for (int ct = 0; ct < 2; ++ct)
          q_s[obase + ct * 16 + ln] = (bf16)(accO[ct][r] * lb);
      }
    }
  }
}

// ---------------------------------------------------------------- k3: proj
// reads bf16 ao from q_s in (B,H,N,32) layout; writes f32 d_out
__global__ void __launch_bounds__(256, 2)
k3_proj(const bf16* __restrict__ xb, const float* __restrict__ pw,
        const float* __restrict__ pbias, float* __restrict__ out) {
  const int tid = threadIdx.x;
  const int wv = tid >> 6, ln = tid & 15, qd = (tid >> 4) & 3;
  const int cg = wv & 1;
  const size_t row0 = (size_t)blockIdx.x * 128 + (wv >> 1) * 64;

  bf16x8 xf[4][4];
#pragma unroll
  for (int nt = 0; nt < 4; ++nt) {
    const size_t row = row0 + nt * 16 + ln;
    const size_t b = row >> 8, n = row & 255;
#pragma unroll
    for (int ks = 0; ks < 4; ++ks)  // dim d = ks*32 + qd*8 + j -> head = ks
      xf[nt][ks] = *(const bf16x8*)(xb + ((b * 4 + ks) * 256 + n) * 32 + qd * 8);
  }

  f32x4 acc[4][4];
#pragma unroll
  for (int mt = 0; mt < 4; ++mt)
#pragma unroll
    for (int nt = 0; nt < 4; ++nt) acc[mt][nt] = (f32x4){0.f, 0.f, 0.f, 0.f};
#pragma unroll
  for (int mt = 0; mt < 4; ++mt)
#pragma unroll
    for (int ks = 0; ks < 4; ++ks) {
      bf16x8 wf = ld_bf8(pw + (size_t)(cg * 64 + mt * 16 + ln) * 128 + ks * 32 + qd * 8);
#pragma unroll
      for (int nt = 0; nt < 4; ++nt) acc[mt][nt] = mfma16(wf, xf[nt][ks], acc[mt][nt]);
    }
#pragma unroll
  for (int mt = 0; mt < 4; ++mt) {
    const int c0 = cg * 64 + mt * 16 + qd * 4;
    f32x4 b4 = *(const f32x4*)(pbias + c0);
#pragma unroll
    for (int nt = 0; nt < 4; ++nt) {
      f32x4 o;
#pragma unroll
      for (int r = 0; r < 4; ++r) o[r] = acc[mt][nt][r] + b4[r];
      *(f32x4*)(out + (row0 + nt * 16 + ln) * 128 + c0) = o;
    }
  }
}

// ----------------------------------------------------------------
extern "C" void kernel_launch(void* const* d_in, const int* in_sizes, int n_in,
                              void* d_out, int out_size, void* d_ws, size_t ws_size,
                              hipStream_t stream) {
  const float* x = (const float*)d_in[0];
  const float* mask = (const float*)d_in[1];
  const float* qkv_w = (const float*)d_in[2];
  const float* qkv_b = (const float*)d_in[3];
  const float* proj_w = (const float*)d_in[4];
  const float* proj_b = (const float*)d_in[5];
  const float* bias_table = (const float*)d_in[6];
  const int* rel_idx = (const int*)d_in[7];

  char* ws = (char*)d_ws;
  bf16* q_s = (bf16*)ws;                      // (B,H,256,32) bf16 33.5MB; ao after k2
  bf16* k_s = (bf16*)(ws + 33554432);         // (B,H,256,32) bf16 33.5 MB
  bf16* vt = (bf16*)(ws + 2ll * 33554432);    // (B,H,32,256) bf16 33.5 MB
  // d_out (67 MB f32) is free scratch until k3: mb (8.4 MB) + rb (0.5 MB) live there
  bf16* mb = (bf16*)d_out;                          // (64,256,256) bf16
  bf16* rb = (bf16*)((char*)d_out + 16777216);      // (4,256,256)  bf16

  k0_prep<<<dim3(4096), dim3(256), 0, stream>>>(mask, bias_table, rel_idx, mb, rb);
  k1_qkv<<<dim3(1024), dim3(256), 0, stream>>>(x, qkv_w, qkv_b, q_s, k_s, vt);
  k2_attn<<<dim3(512), dim3(256), 0, stream>>>(q_s, k_s, vt, mb, rb);
  k3_proj<<<dim3(1024), dim3(256), 0, stream>>>(q_s, proj_w, proj_b, (float*)d_out);
}

// Round 3
// 303.644 us; speedup vs baseline: 1.3231x; 1.0174x over previous
//
#include <hip/hip_runtime.h>

typedef __bf16 bf16;
typedef __bf16 bf16x8 __attribute__((ext_vector_type(8)));
typedef __bf16 bf16x4 __attribute__((ext_vector_type(4)));
typedef float f32x4 __attribute__((ext_vector_type(4)));

static __device__ __forceinline__ f32x4 mfma16(bf16x8 a, bf16x8 b, f32x4 c) {
  return __builtin_amdgcn_mfma_f32_16x16x32_bf16(a, b, c, 0, 0, 0);
}

// load 8 consecutive f32, convert to bf16x8 fragment
static __device__ __forceinline__ bf16x8 ld_bf8(const float* __restrict__ p) {
  f32x4 a = *(const f32x4*)p;
  f32x4 b = *(const f32x4*)(p + 4);
  bf16x8 r;
  r[0] = (bf16)a[0]; r[1] = (bf16)a[1]; r[2] = (bf16)a[2]; r[3] = (bf16)a[3];
  r[4] = (bf16)b[0]; r[5] = (bf16)b[1]; r[6] = (bf16)b[2]; r[7] = (bf16)b[3];
  return r;
}

// ---------------------------------------------------------------- k0w: weights -> bf16
// qkv_w 49152 f32 (12288 f32x4) + proj_w 16384 f32 (4096 f32x4). grid 64.
__global__ void k0w(const float* __restrict__ qw, const float* __restrict__ pw,
                    bf16* __restrict__ wb, bf16* __restrict__ pwb) {
  int t = blockIdx.x * 256 + threadIdx.x;  // 0..16383
  if (t < 12288) {
    f32x4 v = *(const f32x4*)(qw + (size_t)t * 4);
    bf16x4 o;
#pragma unroll
    for (int r = 0; r < 4; ++r) o[r] = (bf16)v[r];
    *(bf16x4*)(wb + (size_t)t * 4) = o;
  } else {
    int u = t - 12288;
    f32x4 v = *(const f32x4*)(pw + (size_t)u * 4);
    bf16x4 o;
#pragma unroll
    for (int r = 0; r < 4; ++r) o[r] = (bf16)v[r];
    *(bf16x4*)(pwb + (size_t)u * 4) = o;
  }
}

// ---------------------------------------------------------------- k1f: fused QKV + prep
// bid < 2048 : qkv, bid = qt*512 + b (XCD = b%8), 64 rows/block
// 2048..3071 : mask -> bf16 (mb), 3072..3327 : rpb gather -> bf16 (rb)
__global__ void __launch_bounds__(256, 4)
k1f(const float* __restrict__ x, const bf16* __restrict__ wb,
    const float* __restrict__ qb, bf16* __restrict__ q_s, bf16* __restrict__ k_s,
    bf16* __restrict__ vt, const float* __restrict__ mask,
    const float* __restrict__ bt, const int* __restrict__ ri,
    bf16* __restrict__ mb, bf16* __restrict__ rb) {
  const int bid = blockIdx.x;
  const int tid = threadIdx.x;
  if (bid >= 2048) {
    if (bid < 3072) {  // mask convert: 1024 blocks x 1024 f32x4
      const int mid = bid - 2048;
#pragma unroll
      for (int it = 0; it < 4; ++it) {
        const size_t t = (size_t)mid * 1024 + it * 256 + tid;
        f32x4 m4 = *(const f32x4*)(mask + t * 4);
        bf16x4 o;
#pragma unroll
        for (int r = 0; r < 4; ++r) o[r] = (bf16)m4[r];
        *(bf16x4*)(mb + t * 4) = o;
      }
    } else {  // rpb gather: 256 blocks
      const int t = (bid - 3072) * 256 + tid;
      const int idx = ri[t];
      f32x4 v = *(const f32x4*)(bt + idx * 4);
#pragma unroll
      for (int h = 0; h < 4; ++h) rb[h * 65536 + t] = (bf16)v[h];
    }
    return;
  }

  const int b = bid & 511, qt = bid >> 9;
  const int wv = tid >> 6, ln = tid & 15, qd = (tid >> 4) & 3;
  const int row0 = qt * 64 + (wv >> 1) * 32;  // local row in batch
  const int cg = wv & 1;

  bf16x8 xf[2][4];  // [nt][ks]
#pragma unroll
  for (int nt = 0; nt < 2; ++nt)
#pragma unroll
    for (int ks = 0; ks < 4; ++ks)
      xf[nt][ks] = ld_bf8(x + (size_t)(b * 256 + row0 + nt * 16 + ln) * 128 +
                          ks * 32 + qd * 8);

  // chunks 0,1 = q,k : transposed (D = W . X^T), bf16 weights direct
#pragma unroll
  for (int ch = 0; ch < 2; ++ch) {
    f32x4 acc[4][2];
#pragma unroll
    for (int mt = 0; mt < 4; ++mt)
#pragma unroll
      for (int nt = 0; nt < 2; ++nt) acc[mt][nt] = (f32x4){0.f, 0.f, 0.f, 0.f};
#pragma unroll
    for (int mt = 0; mt < 4; ++mt)
#pragma unroll
      for (int ks = 0; ks < 4; ++ks) {
        bf16x8 wf = *(const bf16x8*)(wb + (size_t)(ch * 128 + cg * 64 + mt * 16 + ln) *
                                              128 + ks * 32 + qd * 8);
#pragma unroll
        for (int nt = 0; nt < 2; ++nt) acc[mt][nt] = mfma16(wf, xf[nt][ks], acc[mt][nt]);
      }
    bf16* dst = ch ? k_s : q_s;
    const float scl = ch ? 1.0f : 0.17677669529663689f;
#pragma unroll
    for (int mt = 0; mt < 4; ++mt) {
      const int c0 = cg * 64 + mt * 16 + qd * 4;
      f32x4 b4 = *(const f32x4*)(qb + ch * 128 + c0);
      const int hh = c0 >> 5, d0 = c0 & 31;
#pragma unroll
      for (int nt = 0; nt < 2; ++nt) {
        const int nr = row0 + nt * 16 + ln;
        bf16x4 o;
#pragma unroll
        for (int r = 0; r < 4; ++r) o[r] = (bf16)((acc[mt][nt][r] + b4[r]) * scl);
        *(bf16x4*)(dst + (size_t)((b * 4 + hh) * 256 + nr) * 32 + d0) = o;
      }
    }
  }

  // chunk 2 = v : normal orientation -> V^T store
  f32x4 av[2][4];
#pragma unroll
  for (int nt = 0; nt < 2; ++nt)
#pragma unroll
    for (int mt = 0; mt < 4; ++mt) av[nt][mt] = (f32x4){0.f, 0.f, 0.f, 0.f};
#pragma unroll
  for (int ks = 0; ks < 4; ++ks)
#pragma unroll
    for (int mt = 0; mt < 4; ++mt) {
      bf16x8 wf = *(const bf16x8*)(wb + (size_t)(256 + cg * 64 + mt * 16 + ln) * 128 +
                                   ks * 32 + qd * 8);
#pragma unroll
      for (int nt = 0; nt < 2; ++nt) av[nt][mt] = mfma16(xf[nt][ks], wf, av[nt][mt]);
    }
#pragma unroll
  for (int nt = 0; nt < 2; ++nt)
#pragma unroll
    for (int mt = 0; mt < 4; ++mt) {
      const int c = cg * 64 + mt * 16 + ln;
      const float bb = qb[256 + c];
      const int hh = c >> 5, dd = c & 31;
      const int n0 = row0 + nt * 16 + qd * 4;
      bf16x4 o;
#pragma unroll
      for (int r = 0; r < 4; ++r) o[r] = (bf16)(av[nt][mt][r] + bb);
      *(bf16x4*)(vt + (size_t)((b * 4 + hh) * 32 + dd) * 256 + n0) = o;
    }
}

// ---------------------------------------------------------------- k2: attention
// grid 512: bid = rh*256 + h*64 + w ; 256 threads (4 waves, 2 stripes of 16 q-rows)
// S^T = K.Q^T orientation: each lane's 64 logits share one q-row -> softmax = 2 shfl_xor
// ao written bf16 INTO q_s (B,H,N,32) layout: same-wave WAR on fully-consumed Q stripe.
__global__ void __launch_bounds__(256, 2)
k2_attn(bf16* __restrict__ q_s, const bf16* __restrict__ k_s,
        const bf16* __restrict__ vt, const bf16* __restrict__ mb,
        const bf16* __restrict__ rb) {
  __shared__ bf16 ksm[256 * 32];      // K, xor-swizzled 16B blocks
  __shared__ bf16 vsm[32 * 256];      // V^T, xor-swizzled
  __shared__ bf16 psm[4 * 16 * 256];  // P per wave, xor-swizzled
  const int tid = threadIdx.x, wv = tid >> 6;
  const int ln = tid & 15, qd = (tid >> 4) & 3;
  const int w = blockIdx.x & 63, h = (blockIdx.x >> 6) & 3, rh = blockIdx.x >> 8;

  // mask[w]+rpb[h] for this wave's 2 stripes, bf16 loads (8B/lane each)
  bf16x4 cmb[2][16];
#pragma unroll
  for (int si = 0; si < 2; ++si) {
    const int n = (rh * 8 + wv * 2 + si) * 16 + ln;
#pragma unroll
    for (int mt = 0; mt < 16; ++mt) {
      bf16x4 m4 = *(const bf16x4*)(mb + (size_t)(w * 256 + n) * 256 + mt * 16 + qd * 4);
      bf16x4 r4 = *(const bf16x4*)(rb + (size_t)h * 65536 + n * 256 + mt * 16 + qd * 4);
      bf16x4 cv;
#pragma unroll
      for (int r = 0; r < 4; ++r) cv[r] = (bf16)((float)m4[r] + (float)r4[r]);
      cmb[si][mt] = cv;
    }
  }

  for (int ib = 0; ib < 8; ++ib) {
    const int b = w + ib * 64;
    const bf16* kp = k_s + (size_t)(b * 4 + h) * 8192;
    const bf16* vp = vt + (size_t)(b * 4 + h) * 8192;
    __syncthreads();
#pragma unroll
    for (int i = 0; i < 4; ++i) {  // stage K and V^T (16KB each) with swizzle
      const int ci = i * 256 + tid;
      {
        const int r_ = ci >> 2, cb = ci & 3;
        *(bf16x8*)(ksm + r_ * 32 + ((cb ^ (r_ & 3)) * 8)) =
            *(const bf16x8*)(kp + r_ * 32 + cb * 8);
      }
      {
        const int r_ = ci >> 5, cb = ci & 31;
        *(bf16x8*)(vsm + r_ * 256 + ((cb ^ (r_ & 7)) * 8)) =
            *(const bf16x8*)(vp + r_ * 256 + cb * 8);
      }
    }
    __syncthreads();

#pragma unroll
    for (int si = 0; si < 2; ++si) {
      const int s = rh * 8 + wv * 2 + si;
      bf16x8 qf = *(const bf16x8*)(q_s + (size_t)(b * 4 + h) * 8192 +
                                   (s * 16 + ln) * 32 + qd * 8);
      f32x4 acc[16];
#pragma unroll
      for (int mt = 0; mt < 16; ++mt) acc[mt] = (f32x4){0.f, 0.f, 0.f, 0.f};
#pragma unroll
      for (int mt = 0; mt < 16; ++mt) {
        const int m = mt * 16 + ln;
        bf16x8 af = *(const bf16x8*)(ksm + m * 32 + ((qd ^ (m & 3)) * 8));
        acc[mt] = mfma16(af, qf, acc[mt]);  // S^T tile: lane: k=mt*16+qd*4+r, qrow=ln
      }
      float sum = 0.f;
      bf16* pb = psm + wv * 4096 + ln * 256;
#pragma unroll
      for (int mt = 0; mt < 16; ++mt) {  // logits + exp (no max-sub: |logit| < ~8)
        bf16x4 pv;
#pragma unroll
        for (int r = 0; r < 4; ++r) {
          float p = __expf(acc[mt][r] + (float)cmb[si][mt][r]);
          sum += p;
          pv[r] = (bf16)p;
        }
        *(bf16x4*)(pb + (((mt * 2 + (qd >> 1)) ^ (ln & 7)) * 8) + (qd & 1) * 4) = pv;
      }
      sum += __shfl_xor(sum, 16);
      sum += __shfl_xor(sum, 32);
      const float linv = 1.0f / sum;

      f32x4 accO[2];
      accO[0] = (f32x4){0.f, 0.f, 0.f, 0.f};
      accO[1] = (f32x4){0.f, 0.f, 0.f, 0.f};
#pragma unroll
      for (int kt = 0; kt < 8; ++kt) {  // O = P.V
        bf16x8 pf = *(const bf16x8*)(pb + (((kt * 4 + qd) ^ (ln & 7)) * 8));
#pragma unroll
        for (int ct = 0; ct < 2; ++ct) {
          const int d = ct * 16 + ln;
          bf16x8 vf = *(const bf16x8*)(vsm + d * 256 + (((kt * 4 + qd) ^ (d & 7)) * 8));
          accO[ct] = mfma16(pf, vf, accO[ct]);
        }
      }
      // ao (bf16) overwrites this wave's consumed Q stripe: (B,H,N,32) layout
#pragma unroll
      for (int r = 0; r < 4; ++r) {
        const float lb = __shfl(linv, qd * 4 + r);  // row's denom lives at lane ln==row
        const size_t obase =
            (size_t)(b * 4 + h) * 8192 + (size_t)(s * 16 + qd * 4 + r) * 32;
#pragma unroll
        for (int ct = 0; ct < 2; ++ct)
          q_s[obase + ct * 16 + ln] = (bf16)(accO[ct][r] * lb);
      }
    }
  }
}

// ---------------------------------------------------------------- k3: proj
// grid 2048: bid = qt*512 + b (XCD = b%8 matches k2's ao writer), 64 rows/block
// reads bf16 ao from q_s in (B,H,N,32) layout + bf16 weights; writes f32 d_out
__global__ void __launch_bounds__(256, 4)
k3_proj(const bf16* __restrict__ xb, const bf16* __restrict__ pwb,
        const float* __restrict__ pbias, float* __restrict__ out) {
  const int bid = blockIdx.x;
  const int b = bid & 511, qt = bid >> 9;
  const int tid = threadIdx.x;
  const int wv = tid >> 6, ln = tid & 15, qd = (tid >> 4) & 3;
  const int cg = wv & 1;
  const int row0 = qt * 64 + (wv >> 1) * 32;  // local row in batch

  bf16x8 xf[2][4];
#pragma unroll
  for (int nt = 0; nt < 2; ++nt) {
    const int n = row0 + nt * 16 + ln;
#pragma unroll
    for (int ks = 0; ks < 4; ++ks)  // dim d = ks*32 + qd*8 + j -> head = ks
      xf[nt][ks] = *(const bf16x8*)(xb + ((size_t)(b * 4 + ks) * 256 + n) * 32 + qd * 8);
  }

  f32x4 acc[4][2];
#pragma unroll
  for (int mt = 0; mt < 4; ++mt)
#pragma unroll
    for (int nt = 0; nt < 2; ++nt) acc[mt][nt] = (f32x4){0.f, 0.f, 0.f, 0.f};
#pragma unroll
  for (int mt = 0; mt < 4; ++mt)
#pragma unroll
    for (int ks = 0; ks < 4; ++ks) {
      bf16x8 wf = *(const bf16x8*)(pwb + (size_t)(cg * 64 + mt * 16 + ln) * 128 +
                                   ks * 32 + qd * 8);
#pragma unroll
      for (int nt = 0; nt < 2; ++nt) acc[mt][nt] = mfma16(wf, xf[nt][ks], acc[mt][nt]);
    }
#pragma unroll
  for (int mt = 0; mt < 4; ++mt) {
    const int c0 = cg * 64 + mt * 16 + qd * 4;
    f32x4 b4 = *(const f32x4*)(pbias + c0);
#pragma unroll
    for (int nt = 0; nt < 2; ++nt) {
      f32x4 o;
#pragma unroll
      for (int r = 0; r < 4; ++r) o[r] = acc[mt][nt][r] + b4[r];
      *(f32x4*)(out + (size_t)(b * 256 + row0 + nt * 16 + ln) * 128 + c0) = o;
    }
  }
}

// ----------------------------------------------------------------
extern "C" void kernel_launch(void* const* d_in, const int* in_sizes, int n_in,
                              void* d_out, int out_size, void* d_ws, size_t ws_size,
                              hipStream_t stream) {
  const float* x = (const float*)d_in[0];
  const float* mask = (const float*)d_in[1];
  const float* qkv_w = (const float*)d_in[2];
  const float* qkv_b = (const float*)d_in[3];
  const float* proj_w = (const float*)d_in[4];
  const float* proj_b = (const float*)d_in[5];
  const float* bias_table = (const float*)d_in[6];
  const int* rel_idx = (const int*)d_in[7];

  char* ws = (char*)d_ws;
  bf16* q_s = (bf16*)ws;                      // (B,H,256,32) bf16 33.5MB; ao after k2
  bf16* k_s = (bf16*)(ws + 33554432);         // (B,H,256,32) bf16 33.5 MB
  bf16* vt = (bf16*)(ws + 2ll * 33554432);    // (B,H,32,256) bf16 33.5 MB
  bf16* wb = (bf16*)(ws + 3ll * 33554432);            // qkv_w bf16 (384,128) 96KB
  bf16* pwb = (bf16*)(ws + 3ll * 33554432 + 98304);   // proj_w bf16 (128,128) 32KB
  // d_out (67 MB f32) is free scratch until k3: mb (8.4 MB) + rb (0.5 MB) live there
  bf16* mb = (bf16*)d_out;                        // (64,256,256) bf16
  bf16* rb = (bf16*)((char*)d_out + 16777216);    // (4,256,256)  bf16

  k0w<<<dim3(64), dim3(256), 0, stream>>>(qkv_w, proj_w, wb, pwb);
  k1f<<<dim3(3328), dim3(256), 0, stream>>>(x, wb, qkv_b, q_s, k_s, vt, mask,
                                            bias_table, rel_idx, mb, rb);
  k2_attn<<<dim3(512), dim3(256), 0, stream>>>(q_s, k_s, vt, mb, rb);
  k3_proj<<<dim3(2048), dim3(256), 0, stream>>>(q_s, pwb, proj_b, (float*)d_out);
}